// Round 2
// baseline (2357.785 us; speedup 1.0000x reference)
//
#include <hip/hip_runtime.h>
#include <hip/hip_bf16.h>

#define Nb 256
#define Tt 512
#define Dd 64

__device__ __forceinline__ float sigmoidf_(float x) { return 1.0f / (1.0f + __expf(-x)); }
__device__ __forceinline__ float tanhf_(float x) {
    x = fminf(fmaxf(x, -15.0f), 15.0f);
    float e = __expf(2.0f * x);
    return (e - 1.0f) / (e + 1.0f);
}

// One block per batch row n. 256 threads = 4 waves.
// wave0: x_hat, input staging, LSTM cell state; wave1: gamma_h; wave2: z_hat/c_hat/c_c; wave3: beta.
// Every thread owns one column of the 256-wide LSTM gate matmul (weights in registers).
// All data fp32 (reference dtype).
__global__ __launch_bounds__(256, 1) void rits_kernel(
    const float* __restrict__ inp,
    const float* __restrict__ W_hist, const float* __restrict__ b_hist,
    const float* __restrict__ W_feat, const float* __restrict__ b_feat,
    const float* __restrict__ W_gx,   const float* __restrict__ b_gx,
    const float* __restrict__ W_gh,   const float* __restrict__ b_gh,
    const float* __restrict__ W_beta, const float* __restrict__ b_beta,
    const float* __restrict__ W_lstm, const float* __restrict__ U_lstm,
    const float* __restrict__ b_lstm,
    const float* __restrict__ W_out,  const float* __restrict__ b_out,
    float* __restrict__ out)
{
    // Weights packed as float4 along k: s_X[k4*64 + j] = {W[4k4..4k4+3][j]}
    __shared__ __align__(16) float4 s_hist[1024];   // 16 KB
    __shared__ __align__(16) float4 s_feat[1024];   // 16 KB (diagonal zeroed)
    __shared__ __align__(16) float4 s_ghw[1024];    // 16 KB
    __shared__ __align__(16) float4 s_betaW[2048];  // 32 KB
    __shared__ __align__(16) float s_h[64];
    __shared__ __align__(16) float s_d[64];
    __shared__ __align__(16) float s_m[64];
    __shared__ __align__(16) float s_x[64];
    __shared__ __align__(16) float s_cat[128];
    __shared__ __align__(16) float s_xhat[64];
    __shared__ __align__(16) float s_xc[64];
    __shared__ __align__(16) float s_hp[64];
    __shared__ __align__(16) float s_bt[64];
    __shared__ __align__(16) float s_cc[64];
    __shared__ __align__(16) float s_z[256];

    const int tid  = threadIdx.x;
    const int wave = tid >> 6;
    const int j    = tid & 63;
    const int n    = blockIdx.x;

    for (int idx = tid; idx < 1024; idx += 256) {
        int k4 = idx >> 6, jj = idx & 63;
        int k0 = 4 * k4;
        s_hist[idx] = make_float4(W_hist[(k0 + 0) * 64 + jj], W_hist[(k0 + 1) * 64 + jj],
                                  W_hist[(k0 + 2) * 64 + jj], W_hist[(k0 + 3) * 64 + jj]);
        s_feat[idx] = make_float4((k0 + 0 == jj) ? 0.0f : W_feat[(k0 + 0) * 64 + jj],
                                  (k0 + 1 == jj) ? 0.0f : W_feat[(k0 + 1) * 64 + jj],
                                  (k0 + 2 == jj) ? 0.0f : W_feat[(k0 + 2) * 64 + jj],
                                  (k0 + 3 == jj) ? 0.0f : W_feat[(k0 + 3) * 64 + jj]);
        s_ghw[idx] = make_float4(W_gh[(k0 + 0) * 64 + jj], W_gh[(k0 + 1) * 64 + jj],
                                 W_gh[(k0 + 2) * 64 + jj], W_gh[(k0 + 3) * 64 + jj]);
    }
    for (int idx = tid; idx < 2048; idx += 256) {
        int k4 = idx >> 6, jj = idx & 63;
        int k0 = 4 * k4;
        s_betaW[idx] = make_float4(W_beta[(k0 + 0) * 64 + jj], W_beta[(k0 + 1) * 64 + jj],
                                   W_beta[(k0 + 2) * 64 + jj], W_beta[(k0 + 3) * 64 + jj]);
    }

    // Register-resident LSTM gate weights: column `tid`
    float wl[128];
    float wu[64];
#pragma unroll
    for (int k = 0; k < 128; ++k) wl[k] = W_lstm[k * 256 + tid];
#pragma unroll
    for (int k = 0; k < 64; ++k)  wu[k] = U_lstm[k * 256 + tid];
    const float bl = b_lstm[tid];

    float bh = 0, gxw = 0, gxb = 0, wout = 0, bo = 0, bgh = 0, bft = 0, bb = 0;
    if (wave == 0) {
        bh   = b_hist[j];
        gxw  = W_gx[j * 64 + j];   // diagonal constraint
        gxb  = b_gx[j];
        wout = W_out[j];
        bo   = b_out[0];
        s_h[j] = 0.0f;
    } else if (wave == 1) { bgh = b_gh[j]; }
    else if (wave == 2)   { bft = b_feat[j]; }
    else                  { bb  = b_beta[j]; }

    float c = 0.0f;
    const size_t base = (size_t)n * (3 * Tt * Dd);
    float nx = 0, nm = 0, nd = 0;
    if (wave == 0) {
        nx = inp[base + j];
        nm = inp[base + Tt * Dd + j];
        nd = inp[base + 2 * Tt * Dd + j];
    }
    __syncthreads();

    float xr = 0, mr = 0, dr = 0;
#pragma unroll 1
    for (int t = 0; t < Tt; ++t) {
        // ---- S1: stage inputs for step t, prefetch t+1, gamma_x
        if (wave == 0) {
            xr = nx; mr = nm; dr = nd;
            s_x[j] = xr; s_m[j] = mr; s_d[j] = dr;
            float gx = __expf(-fmaxf(fmaf(dr, gxw, gxb), 0.0f));
            s_cat[j] = gx; s_cat[64 + j] = mr;
            if (t + 1 < Tt) {
                nx = inp[base + (t + 1) * Dd + j];
                nm = inp[base + Tt * Dd + (t + 1) * Dd + j];
                nd = inp[base + 2 * Tt * Dd + (t + 1) * Dd + j];
            }
        }
        __syncthreads();

        // ---- S2: x_hat | gamma_h*h | beta ; all waves: m-part of z
        float zacc = bl;
        {
            const float4* m4 = reinterpret_cast<const float4*>(s_m);
#pragma unroll
            for (int k4 = 0; k4 < 16; ++k4) {
                float4 v = m4[k4];
                zacc = fmaf(v.x, wl[64 + 4 * k4 + 0], zacc);
                zacc = fmaf(v.y, wl[64 + 4 * k4 + 1], zacc);
                zacc = fmaf(v.z, wl[64 + 4 * k4 + 2], zacc);
                zacc = fmaf(v.w, wl[64 + 4 * k4 + 3], zacc);
            }
        }
        if (wave == 0) {
            float acc = bh;
            const float4* h4 = reinterpret_cast<const float4*>(s_h);
#pragma unroll
            for (int k4 = 0; k4 < 16; ++k4) {
                float4 w = s_hist[(k4 << 6) + j];
                float4 v = h4[k4];
                acc = fmaf(v.x, w.x, acc); acc = fmaf(v.y, w.y, acc);
                acc = fmaf(v.z, w.z, acc); acc = fmaf(v.w, w.w, acc);
            }
            s_xhat[j] = acc;
            s_xc[j] = fmaf(mr, xr, (1.0f - mr) * acc);
            out[(size_t)((n * 3 + 0) * Tt + t) * Dd + j] = acc;
        } else if (wave == 1) {
            float acc = bgh;
            const float4* d4 = reinterpret_cast<const float4*>(s_d);
#pragma unroll
            for (int k4 = 0; k4 < 16; ++k4) {
                float4 w = s_ghw[(k4 << 6) + j];
                float4 v = d4[k4];
                acc = fmaf(v.x, w.x, acc); acc = fmaf(v.y, w.y, acc);
                acc = fmaf(v.z, w.z, acc); acc = fmaf(v.w, w.w, acc);
            }
            float gh = __expf(-fmaxf(acc, 0.0f));
            s_hp[j] = s_h[j] * gh;
        } else if (wave == 3) {
            float acc = bb;
            const float4* c4 = reinterpret_cast<const float4*>(s_cat);
#pragma unroll
            for (int k4 = 0; k4 < 32; ++k4) {
                float4 w = s_betaW[(k4 << 6) + j];
                float4 v = c4[k4];
                acc = fmaf(v.x, w.x, acc); acc = fmaf(v.y, w.y, acc);
                acc = fmaf(v.z, w.z, acc); acc = fmaf(v.w, w.w, acc);
            }
            s_bt[j] = sigmoidf_(acc);
        }
        __syncthreads();

        // ---- S3: wave2: z_hat -> c_hat -> c_c ; others: U-part of z
        if (wave == 2) {
            float acc = bft;
            const float4* x4 = reinterpret_cast<const float4*>(s_xc);
#pragma unroll
            for (int k4 = 0; k4 < 16; ++k4) {
                float4 w = s_feat[(k4 << 6) + j];
                float4 v = x4[k4];
                acc = fmaf(v.x, w.x, acc); acc = fmaf(v.y, w.y, acc);
                acc = fmaf(v.z, w.z, acc); acc = fmaf(v.w, w.w, acc);
            }
            float bt = s_bt[j];
            float chat = bt * acc + (1.0f - bt) * s_xhat[j];
            float mj = s_m[j], xj = s_x[j];
            s_cc[j] = fmaf(mj, xj, (1.0f - mj) * chat);
            out[(size_t)((n * 3 + 1) * Tt + t) * Dd + j] = acc;
            out[(size_t)((n * 3 + 2) * Tt + t) * Dd + j] = chat;
        } else {
            const float4* h4 = reinterpret_cast<const float4*>(s_hp);
#pragma unroll
            for (int k4 = 0; k4 < 16; ++k4) {
                float4 v = h4[k4];
                zacc = fmaf(v.x, wu[4 * k4 + 0], zacc);
                zacc = fmaf(v.y, wu[4 * k4 + 1], zacc);
                zacc = fmaf(v.z, wu[4 * k4 + 2], zacc);
                zacc = fmaf(v.w, wu[4 * k4 + 3], zacc);
            }
        }
        __syncthreads();

        // ---- S4: finish z (cc-part; wave2 also its U-part), publish to s_z
        if (wave == 2) {
            const float4* h4 = reinterpret_cast<const float4*>(s_hp);
#pragma unroll
            for (int k4 = 0; k4 < 16; ++k4) {
                float4 v = h4[k4];
                zacc = fmaf(v.x, wu[4 * k4 + 0], zacc);
                zacc = fmaf(v.y, wu[4 * k4 + 1], zacc);
                zacc = fmaf(v.z, wu[4 * k4 + 2], zacc);
                zacc = fmaf(v.w, wu[4 * k4 + 3], zacc);
            }
        }
        {
            const float4* c4 = reinterpret_cast<const float4*>(s_cc);
#pragma unroll
            for (int k4 = 0; k4 < 16; ++k4) {
                float4 v = c4[k4];
                zacc = fmaf(v.x, wl[4 * k4 + 0], zacc);
                zacc = fmaf(v.y, wl[4 * k4 + 1], zacc);
                zacc = fmaf(v.z, wl[4 * k4 + 2], zacc);
                zacc = fmaf(v.w, wl[4 * k4 + 3], zacc);
            }
        }
        s_z[tid] = zacc;
        __syncthreads();

        // ---- S5: LSTM cell update (wave0). Next-iter S1 barrier protects s_h/s_z.
        if (wave == 0) {
            float zi = s_z[j], zf = s_z[64 + j], zg = s_z[128 + j], zo = s_z[192 + j];
            c = sigmoidf_(zf) * c + sigmoidf_(zi) * tanhf_(zg);
            float hn = sigmoidf_(zo) * tanhf_(c);
            s_h[j] = hn;
            if (t == Tt - 1) {
                float p = hn * wout;
#pragma unroll
                for (int off = 32; off > 0; off >>= 1) p += __shfl_down(p, off, 64);
                if (j == 0)
                    out[(size_t)Nb * 3 * Tt * Dd + n] = sigmoidf_(p + bo);
            }
        }
    }
}

extern "C" void kernel_launch(void* const* d_in, const int* in_sizes, int n_in,
                              void* d_out, int out_size, void* d_ws, size_t ws_size,
                              hipStream_t stream) {
    (void)in_sizes; (void)n_in; (void)out_size; (void)d_ws; (void)ws_size;
    const float* inp    = (const float*)d_in[0];
    const float* W_hist = (const float*)d_in[1];
    const float* b_hist = (const float*)d_in[2];
    const float* W_feat = (const float*)d_in[3];
    const float* b_feat = (const float*)d_in[4];
    const float* W_gx   = (const float*)d_in[5];
    const float* b_gx   = (const float*)d_in[6];
    const float* W_gh   = (const float*)d_in[7];
    const float* b_gh   = (const float*)d_in[8];
    const float* W_beta = (const float*)d_in[9];
    const float* b_beta = (const float*)d_in[10];
    const float* W_lstm = (const float*)d_in[11];
    const float* U_lstm = (const float*)d_in[12];
    const float* b_lstm = (const float*)d_in[13];
    const float* W_out  = (const float*)d_in[14];
    const float* b_out  = (const float*)d_in[15];
    float* out = (float*)d_out;

    rits_kernel<<<dim3(Nb), dim3(256), 0, stream>>>(
        inp, W_hist, b_hist, W_feat, b_feat, W_gx, b_gx, W_gh, b_gh,
        W_beta, b_beta, W_lstm, U_lstm, b_lstm, W_out, b_out, out);
}

// Round 3
// 1588.523 us; speedup vs baseline: 1.4843x; 1.4843x over previous
//
#include <hip/hip_runtime.h>
#include <hip/hip_bf16.h>

#define Nb 256
#define Tt 512
#define Dd 64
#define TD (Tt * Dd)

__device__ __forceinline__ float sigmoidf_(float x) { return 1.0f / (1.0f + __expf(-x)); }
__device__ __forceinline__ float tanhf_(float x) {
    x = fminf(fmaxf(x, -15.0f), 15.0f);
    float e = __expf(2.0f * x);
    return (e - 1.0f) / (e + 1.0f);
}
// Barrier that drains ONLY LDS (cross-wave data is LDS-only here).
// Global stores + prefetch loads stay in flight — no vmcnt(0) drain.
__device__ __forceinline__ void bar_lds() {
    asm volatile("s_waitcnt lgkmcnt(0)\n\ts_barrier" ::: "memory");
}

// One block per batch row. 4 waves, all weights register-resident.
// z-columns: wave w owns all 4 gates of h-elements j in [16w,16w+16)
// -> LSTM cell update is in-wave via shuffles (no extra barrier).
__global__ __launch_bounds__(256, 1) void rits_kernel(
    const float* __restrict__ inp,
    const float* __restrict__ W_hist, const float* __restrict__ b_hist,
    const float* __restrict__ W_feat, const float* __restrict__ b_feat,
    const float* __restrict__ W_gx,   const float* __restrict__ b_gx,
    const float* __restrict__ W_gh,   const float* __restrict__ b_gh,
    const float* __restrict__ W_beta, const float* __restrict__ b_beta,
    const float* __restrict__ W_lstm, const float* __restrict__ U_lstm,
    const float* __restrict__ b_lstm,
    const float* __restrict__ W_out,  const float* __restrict__ b_out,
    float* __restrict__ out)
{
    __shared__ __align__(16) float s_h[64];
    __shared__ __align__(16) float s_d[64];
    __shared__ __align__(16) float s_m[64];
    __shared__ __align__(16) float s_x[64];
    __shared__ __align__(16) float s_cat[128];
    __shared__ __align__(16) float s_xhat[64];
    __shared__ __align__(16) float s_xc[64];
    __shared__ __align__(16) float s_hp[64];
    __shared__ __align__(16) float s_bt[64];
    __shared__ __align__(16) float s_cc[64];

    const int tid  = threadIdx.x;
    const int wave = tid >> 6;
    const int j    = tid & 63;
    const int jl   = j & 15;
    const int gate = j >> 4;
    const int n    = blockIdx.x;

    // z column owned by this thread: gate*64 + 16*wave + jl
    const int col = (gate << 6) + (wave << 4) + jl;

    // ---- register-resident weights ----
    float wl[128], wu[64];
#pragma unroll
    for (int k = 0; k < 128; ++k) wl[k] = W_lstm[k * 256 + col];
#pragma unroll
    for (int k = 0; k < 64; ++k)  wu[k] = U_lstm[k * 256 + col];
    const float bl = b_lstm[col];

    // per-wave specialized matrix column j
    const float* Wsel = (wave == 0) ? W_hist : (wave == 1) ? W_gh
                      : (wave == 2) ? W_feat : W_beta;
    float wA[64];
#pragma unroll
    for (int k = 0; k < 64; ++k)
        wA[k] = (wave == 2 && k == j) ? 0.0f : Wsel[k * 64 + j];  // zero-diag for W_feat
    float wB[64];
    if (wave == 3) {
#pragma unroll
        for (int k = 0; k < 64; ++k) wB[k] = W_beta[(64 + k) * 64 + j];
    } else {
#pragma unroll
        for (int k = 0; k < 64; ++k) wB[k] = 0.0f;
    }
    const float bwv = (wave == 0) ? b_hist[j] : (wave == 1) ? b_gh[j]
                    : (wave == 2) ? b_feat[j] : b_beta[j];

    float gxw = 0, gxb = 0, wout = 0, bo = 0;
    if (wave == 0) {
        gxw = W_gx[j * 64 + j]; gxb = b_gx[j];
        wout = W_out[j]; bo = b_out[0];
    }

    const size_t base = (size_t)n * (3 * TD);
    float nx = 0, nm = 0, nd = 0;
    float c = 0.0f;

    if (wave == 0) {
        float x0 = inp[base + j], m0 = inp[base + TD + j], d0 = inp[base + 2 * TD + j];
        s_x[j] = x0; s_m[j] = m0; s_d[j] = d0;
        s_cat[j] = __expf(-fmaxf(fmaf(d0, gxw, gxb), 0.0f));
        s_cat[64 + j] = m0;
        nx = inp[base + Dd + j];
        nm = inp[base + TD + Dd + j];
        nd = inp[base + 2 * TD + Dd + j];
    } else if (wave == 1) {
        s_h[j] = 0.0f;
    }
    bar_lds();

#pragma unroll 1
    for (int t = 0; t < Tt; ++t) {
        float z0 = 0, z1 = 0, z2 = 0, z3 = 0;

        // ==== Stage A: x_hat | gamma_h | beta ; waves 0-2: m-part of z ====
        if (wave != 3) {
            const float4* m4 = reinterpret_cast<const float4*>(s_m);
#pragma unroll
            for (int k4 = 0; k4 < 16; ++k4) {
                float4 v = m4[k4];
                z0 = fmaf(v.x, wl[64 + 4 * k4 + 0], z0);
                z1 = fmaf(v.y, wl[64 + 4 * k4 + 1], z1);
                z2 = fmaf(v.z, wl[64 + 4 * k4 + 2], z2);
                z3 = fmaf(v.w, wl[64 + 4 * k4 + 3], z3);
            }
        }
        if (wave == 0) {
            float a0 = 0, a1 = 0, a2 = 0, a3 = 0;
            const float4* h4 = reinterpret_cast<const float4*>(s_h);
#pragma unroll
            for (int k4 = 0; k4 < 16; ++k4) {
                float4 v = h4[k4];
                a0 = fmaf(v.x, wA[4 * k4 + 0], a0); a1 = fmaf(v.y, wA[4 * k4 + 1], a1);
                a2 = fmaf(v.z, wA[4 * k4 + 2], a2); a3 = fmaf(v.w, wA[4 * k4 + 3], a3);
            }
            float acc = bwv + ((a0 + a1) + (a2 + a3));
            s_xhat[j] = acc;
            float xr = s_x[j], mr = s_m[j];
            s_xc[j] = fmaf(mr, xr, (1.0f - mr) * acc);
            out[(size_t)((n * 3 + 0) * Tt + t) * Dd + j] = acc;
        } else if (wave == 1) {
            float a0 = 0, a1 = 0, a2 = 0, a3 = 0;
            const float4* d4 = reinterpret_cast<const float4*>(s_d);
#pragma unroll
            for (int k4 = 0; k4 < 16; ++k4) {
                float4 v = d4[k4];
                a0 = fmaf(v.x, wA[4 * k4 + 0], a0); a1 = fmaf(v.y, wA[4 * k4 + 1], a1);
                a2 = fmaf(v.z, wA[4 * k4 + 2], a2); a3 = fmaf(v.w, wA[4 * k4 + 3], a3);
            }
            float acc = bwv + ((a0 + a1) + (a2 + a3));
            float gh = __expf(-fmaxf(acc, 0.0f));
            s_hp[j] = s_h[j] * gh;
        } else if (wave == 3) {
            float a0 = 0, a1 = 0, a2 = 0, a3 = 0;
            const float4* c4 = reinterpret_cast<const float4*>(s_cat);
#pragma unroll
            for (int k4 = 0; k4 < 16; ++k4) {
                float4 v = c4[k4];
                a0 = fmaf(v.x, wA[4 * k4 + 0], a0); a1 = fmaf(v.y, wA[4 * k4 + 1], a1);
                a2 = fmaf(v.z, wA[4 * k4 + 2], a2); a3 = fmaf(v.w, wA[4 * k4 + 3], a3);
            }
#pragma unroll
            for (int k4 = 0; k4 < 16; ++k4) {
                float4 v = c4[16 + k4];
                a0 = fmaf(v.x, wB[4 * k4 + 0], a0); a1 = fmaf(v.y, wB[4 * k4 + 1], a1);
                a2 = fmaf(v.z, wB[4 * k4 + 2], a2); a3 = fmaf(v.w, wB[4 * k4 + 3], a3);
            }
            s_bt[j] = sigmoidf_(bwv + ((a0 + a1) + (a2 + a3)));
        }
        bar_lds();

        // ==== Stage B: all: U-part of z ; wave2: z_hat->c_hat->cc ; wave3: m-part ====
        {
            const float4* h4 = reinterpret_cast<const float4*>(s_hp);
#pragma unroll
            for (int k4 = 0; k4 < 16; ++k4) {
                float4 v = h4[k4];
                z0 = fmaf(v.x, wu[4 * k4 + 0], z0);
                z1 = fmaf(v.y, wu[4 * k4 + 1], z1);
                z2 = fmaf(v.z, wu[4 * k4 + 2], z2);
                z3 = fmaf(v.w, wu[4 * k4 + 3], z3);
            }
        }
        if (wave == 3) {
            const float4* m4 = reinterpret_cast<const float4*>(s_m);
#pragma unroll
            for (int k4 = 0; k4 < 16; ++k4) {
                float4 v = m4[k4];
                z0 = fmaf(v.x, wl[64 + 4 * k4 + 0], z0);
                z1 = fmaf(v.y, wl[64 + 4 * k4 + 1], z1);
                z2 = fmaf(v.z, wl[64 + 4 * k4 + 2], z2);
                z3 = fmaf(v.w, wl[64 + 4 * k4 + 3], z3);
            }
        } else if (wave == 2) {
            float a0 = 0, a1 = 0, a2 = 0, a3 = 0;
            const float4* x4 = reinterpret_cast<const float4*>(s_xc);
#pragma unroll
            for (int k4 = 0; k4 < 16; ++k4) {
                float4 v = x4[k4];
                a0 = fmaf(v.x, wA[4 * k4 + 0], a0); a1 = fmaf(v.y, wA[4 * k4 + 1], a1);
                a2 = fmaf(v.z, wA[4 * k4 + 2], a2); a3 = fmaf(v.w, wA[4 * k4 + 3], a3);
            }
            float acc = bwv + ((a0 + a1) + (a2 + a3));
            float bt = s_bt[j];
            float chat = bt * acc + (1.0f - bt) * s_xhat[j];
            float mj = s_m[j], xj = s_x[j];
            s_cc[j] = fmaf(mj, xj, (1.0f - mj) * chat);
            out[(size_t)((n * 3 + 1) * Tt + t) * Dd + j] = acc;
            out[(size_t)((n * 3 + 2) * Tt + t) * Dd + j] = chat;
        }
        bar_lds();

        // ==== Stage C: all: cc-part of z ; in-wave LSTM update ; wave0: stage t+1 ====
        {
            const float4* c4 = reinterpret_cast<const float4*>(s_cc);
#pragma unroll
            for (int k4 = 0; k4 < 16; ++k4) {
                float4 v = c4[k4];
                z0 = fmaf(v.x, wl[4 * k4 + 0], z0);
                z1 = fmaf(v.y, wl[4 * k4 + 1], z1);
                z2 = fmaf(v.z, wl[4 * k4 + 2], z2);
                z3 = fmaf(v.w, wl[4 * k4 + 3], z3);
            }
        }
        float z = bl + ((z0 + z1) + (z2 + z3));
        float zi = __shfl(z, jl, 64);
        float zf = __shfl(z, 16 + jl, 64);
        float zg = __shfl(z, 32 + jl, 64);
        float zo = __shfl(z, 48 + jl, 64);
        c = sigmoidf_(zf) * c + sigmoidf_(zi) * tanhf_(zg);
        float hn = sigmoidf_(zo) * tanhf_(c);
        if (gate == 0) s_h[(wave << 4) + jl] = hn;

        if (wave == 0 && t + 1 < Tt) {
            s_x[j] = nx; s_m[j] = nm; s_d[j] = nd;
            s_cat[j] = __expf(-fmaxf(fmaf(nd, gxw, gxb), 0.0f));
            s_cat[64 + j] = nm;
            if (t + 2 < Tt) {
                nx = inp[base + (t + 2) * Dd + j];
                nm = inp[base + TD + (t + 2) * Dd + j];
                nd = inp[base + 2 * TD + (t + 2) * Dd + j];
            }
        }
        bar_lds();
    }

    // final prediction: sigmoid(h_last @ W_out + b_out)
    if (wave == 0) {
        float p = s_h[j] * wout;
#pragma unroll
        for (int off = 32; off > 0; off >>= 1) p += __shfl_down(p, off, 64);
        if (j == 0) out[(size_t)Nb * 3 * TD + n] = sigmoidf_(p + bo);
    }
}

extern "C" void kernel_launch(void* const* d_in, const int* in_sizes, int n_in,
                              void* d_out, int out_size, void* d_ws, size_t ws_size,
                              hipStream_t stream) {
    (void)in_sizes; (void)n_in; (void)out_size; (void)d_ws; (void)ws_size;
    const float* inp    = (const float*)d_in[0];
    const float* W_hist = (const float*)d_in[1];
    const float* b_hist = (const float*)d_in[2];
    const float* W_feat = (const float*)d_in[3];
    const float* b_feat = (const float*)d_in[4];
    const float* W_gx   = (const float*)d_in[5];
    const float* b_gx   = (const float*)d_in[6];
    const float* W_gh   = (const float*)d_in[7];
    const float* b_gh   = (const float*)d_in[8];
    const float* W_beta = (const float*)d_in[9];
    const float* b_beta = (const float*)d_in[10];
    const float* W_lstm = (const float*)d_in[11];
    const float* U_lstm = (const float*)d_in[12];
    const float* b_lstm = (const float*)d_in[13];
    const float* W_out  = (const float*)d_in[14];
    const float* b_out  = (const float*)d_in[15];
    float* out = (float*)d_out;

    rits_kernel<<<dim3(Nb), dim3(256), 0, stream>>>(
        inp, W_hist, b_hist, W_feat, b_feat, W_gx, b_gx, W_gh, b_gh,
        W_beta, b_beta, W_lstm, U_lstm, b_lstm, W_out, b_out, out);
}